// Round 4
// baseline (1043.760 us; speedup 1.0000x reference)
//
#include <hip/hip_runtime.h>

#define F_IN 64
#define F_OUT 40
#define F4 (F_OUT / 4)        // 10 float4 per row

#define SCAN_BLK 256
#define SCAN_ELEMS 4
#define SCAN_TILE (SCAN_BLK * SCAN_ELEMS)   // 1024 elems per block
#define NBIN 1024                           // degree histogram bins

// ---------------- degree histogram (int) ----------------
__global__ void deg_count_kernel(const int* __restrict__ dst, int E, int* __restrict__ deg) {
    int e = blockIdx.x * blockDim.x + threadIdx.x;
    if (e < E) atomicAdd(&deg[dst[e]], 1);
}

// dinv = rsqrt(deg+1), dinv2 = dinv^2; also degree histogram for the perm sort
__global__ void dinv_kernel(const int* __restrict__ deg, float* __restrict__ dinv,
                            float* __restrict__ dinv2, int* __restrict__ dhist, int n) {
    int i = blockIdx.x * blockDim.x + threadIdx.x;
    if (i >= n) return;
    int d = deg[i];
    float r = rsqrtf((float)d + 1.0f);
    dinv[i] = r;
    dinv2[i] = r * r;
    atomicAdd(&dhist[min(d, NBIN - 1)], 1);
}

// ---------------- hierarchical scan: A) per-block reduce ----------------
__global__ __launch_bounds__(SCAN_BLK) void scan_a_kernel(const int* __restrict__ deg,
                                                          int* __restrict__ bsum, int n) {
    __shared__ int s[SCAN_BLK];
    int tid = threadIdx.x;
    int base = blockIdx.x * SCAN_TILE + tid * SCAN_ELEMS;
    int local = 0;
#pragma unroll
    for (int k = 0; k < SCAN_ELEMS; ++k) {
        int i = base + k;
        if (i < n) local += deg[i];
    }
    s[tid] = local;
    __syncthreads();
    for (int off = SCAN_BLK / 2; off > 0; off >>= 1) {
        if (tid < off) s[tid] += s[tid + off];
        __syncthreads();
    }
    if (tid == 0) bsum[blockIdx.x] = s[0];
}

// ---------------- B) single-block scan of <=256 partials ----------------
__global__ __launch_bounds__(256) void scan_b_kernel(int* __restrict__ bsum,
                                                     int* __restrict__ total_out, int nb) {
    __shared__ int s[256];
    int tid = threadIdx.x;
    int v = (tid < nb) ? bsum[tid] : 0;
    s[tid] = v;
    __syncthreads();
    for (int off = 1; off < 256; off <<= 1) {
        int t = (tid >= off) ? s[tid - off] : 0;
        __syncthreads();
        s[tid] += t;
        __syncthreads();
    }
    if (tid < nb) bsum[tid] = s[tid] - v;     // exclusive block offset
    if (tid == 255) *total_out = s[255];      // rowptr[n]
}

// ---------------- C) per-block local scan + offset -> rowptr & cursor ----------------
__global__ __launch_bounds__(SCAN_BLK) void scan_c_kernel(const int* __restrict__ deg,
                                                          const int* __restrict__ boff,
                                                          int* __restrict__ rowptr,
                                                          int* __restrict__ cursor, int n) {
    __shared__ int s[SCAN_BLK];
    int tid = threadIdx.x;
    int base = blockIdx.x * SCAN_TILE + tid * SCAN_ELEMS;
    int vals[SCAN_ELEMS];
    int local = 0;
#pragma unroll
    for (int k = 0; k < SCAN_ELEMS; ++k) {
        int i = base + k;
        vals[k] = (i < n) ? deg[i] : 0;
        local += vals[k];
    }
    s[tid] = local;
    __syncthreads();
    for (int off = 1; off < SCAN_BLK; off <<= 1) {
        int t = (tid >= off) ? s[tid - off] : 0;
        __syncthreads();
        s[tid] += t;
        __syncthreads();
    }
    int prefix = boff[blockIdx.x] + s[tid] - local;
#pragma unroll
    for (int k = 0; k < SCAN_ELEMS; ++k) {
        int i = base + k;
        if (i < n) {
            rowptr[i] = prefix;
            cursor[i] = prefix;
            prefix += vals[k];
        }
    }
}

// ---------------- degree-bin scan (1024 bins, one block) -> bin cursors ----------------
__global__ __launch_bounds__(1024) void binscan_kernel(const int* __restrict__ dhist,
                                                       int* __restrict__ bincur) {
    __shared__ int s[NBIN];
    int tid = threadIdx.x;
    int v = dhist[tid];
    s[tid] = v;
    __syncthreads();
    for (int off = 1; off < NBIN; off <<= 1) {
        int t = (tid >= off) ? s[tid - off] : 0;
        __syncthreads();
        s[tid] += t;
        __syncthreads();
    }
    bincur[tid] = s[tid] - v;   // exclusive
}

// ---------------- build degree-sorted node permutation ----------------
__global__ void perm_kernel(const int* __restrict__ deg, int* __restrict__ bincur,
                            int* __restrict__ perm, int n) {
    int i = blockIdx.x * blockDim.x + threadIdx.x;
    if (i >= n) return;
    int b = min(deg[i], NBIN - 1);
    int pos = atomicAdd(&bincur[b], 1);
    perm[pos] = i;
}

// ---------------- reorder edges by dst: record = src index only (4B) ----------------
__global__ void reorder_kernel(const int* __restrict__ src, const int* __restrict__ dst,
                               int* __restrict__ cursor, int* __restrict__ srcs_sorted, int E) {
    int e = blockIdx.x * blockDim.x + threadIdx.x;
    if (e >= E) return;
    int r = src[e];
    int c = dst[e];
    int pos = atomicAdd(&cursor[c], 1);
    srcs_sorted[pos] = r;
}

// ---------------- projection u0 = dinv * (x @ W^T) ----------------
__global__ __launch_bounds__(256) void proj_kernel(const float* __restrict__ x,
                                                   const float* __restrict__ W,
                                                   const float* __restrict__ dinv,
                                                   float* __restrict__ u, int n) {
    __shared__ float Ws[F_OUT * F_IN];
    for (int i = threadIdx.x; i < F_OUT * F_IN; i += blockDim.x) Ws[i] = W[i];
    __syncthreads();

    int node = blockIdx.x * blockDim.x + threadIdx.x;
    if (node >= n) return;

    const float4* xp  = (const float4*)(x + (size_t)node * F_IN);
    const float4* Ws4 = (const float4*)Ws;

    float acc[F_OUT];
#pragma unroll
    for (int c = 0; c < F_OUT; ++c) acc[c] = 0.0f;

#pragma unroll
    for (int f4 = 0; f4 < F_IN / 4; ++f4) {
        float4 xv = xp[f4];
#pragma unroll
        for (int c = 0; c < F_OUT; ++c) {
            float4 w = Ws4[c * (F_IN / 4) + f4];
            acc[c] += xv.x * w.x + xv.y * w.y + xv.z * w.z + xv.w * w.w;
        }
    }

    float dv = dinv[node];
    float4* up = (float4*)(u + (size_t)node * F_OUT);
#pragma unroll
    for (int c4 = 0; c4 < F4; ++c4) {
        float4 v;
        v.x = dv * acc[4 * c4 + 0]; v.y = dv * acc[4 * c4 + 1];
        v.z = dv * acc[4 * c4 + 2]; v.w = dv * acc[4 * c4 + 3];
        up[c4] = v;
    }
}

// ---------------- pull propagation in u-space: u' = dinv2 * ((A u) + u) ----------------
// Nodes processed in degree-sorted order (perm) so waves have uniform loop trip counts.
// thread t handles (node = perm[t/10], f4 = t%10): one float4 of the output row.
__global__ __launch_bounds__(256) void propagate_kernel(const int* __restrict__ perm,
                                                        const int* __restrict__ rowptr,
                                                        const int* __restrict__ srcs,
                                                        const float* __restrict__ dinv2,
                                                        const float* __restrict__ ucur,
                                                        float* __restrict__ unew, int n) {
    int t = blockIdx.x * blockDim.x + threadIdx.x;
    int g = t / F4;
    int f4 = t - g * F4;
    if (g >= n) return;
    int node = perm[g];

    int beg = rowptr[node];
    int end = rowptr[node + 1];

    const float4* u4 = (const float4*)ucur;
    // self loop term
    float4 acc = u4[(size_t)node * F4 + f4];

    int i = beg;
    for (; i + 1 < end; i += 2) {          // unroll x2 for ILP
        int s0 = srcs[i];
        int s1 = srcs[i + 1];
        float4 v0 = u4[(size_t)s0 * F4 + f4];
        float4 v1 = u4[(size_t)s1 * F4 + f4];
        acc.x += v0.x; acc.y += v0.y; acc.z += v0.z; acc.w += v0.w;
        acc.x += v1.x; acc.y += v1.y; acc.z += v1.z; acc.w += v1.w;
    }
    if (i < end) {
        float4 v = u4[(size_t)srcs[i] * F4 + f4];
        acc.x += v.x; acc.y += v.y; acc.z += v.z; acc.w += v.w;
    }

    float ds = dinv2[node];
    acc.x *= ds; acc.y *= ds; acc.z *= ds; acc.w *= ds;
    ((float4*)unew)[(size_t)node * F4 + f4] = acc;
}

// ---------------- bias + log_softmax, with final y = D^{1/2} u scale ----------------
__global__ void logsoftmax_kernel(float* __restrict__ out, const float* __restrict__ bias,
                                  const int* __restrict__ deg, int n) {
    int node = blockIdx.x * blockDim.x + threadIdx.x;
    if (node >= n) return;
    float sq = sqrtf((float)deg[node] + 1.0f);   // 1/dinv
    float4* p = (float4*)(out + (size_t)node * F_OUT);
    float v[F_OUT];
#pragma unroll
    for (int c4 = 0; c4 < F4; ++c4) {
        float4 t = p[c4];
        v[4 * c4 + 0] = sq * t.x + bias[4 * c4 + 0];
        v[4 * c4 + 1] = sq * t.y + bias[4 * c4 + 1];
        v[4 * c4 + 2] = sq * t.z + bias[4 * c4 + 2];
        v[4 * c4 + 3] = sq * t.w + bias[4 * c4 + 3];
    }
    float mx = -1e30f;
#pragma unroll
    for (int c = 0; c < F_OUT; ++c) mx = fmaxf(mx, v[c]);
    float se = 0.0f;
#pragma unroll
    for (int c = 0; c < F_OUT; ++c) se += __expf(v[c] - mx);
    float lse = mx + __logf(se);
#pragma unroll
    for (int c4 = 0; c4 < F4; ++c4) {
        float4 t;
        t.x = v[4 * c4 + 0] - lse; t.y = v[4 * c4 + 1] - lse;
        t.z = v[4 * c4 + 2] - lse; t.w = v[4 * c4 + 3] - lse;
        p[c4] = t;
    }
}

extern "C" void kernel_launch(void* const* d_in, const int* in_sizes, int n_in,
                              void* d_out, int out_size, void* d_ws, size_t ws_size,
                              hipStream_t stream) {
    const float* x  = (const float*)d_in[0];
    const int*   ei = (const int*)d_in[1];
    const float* W  = (const float*)d_in[2];
    const float* b  = (const float*)d_in[3];

    const int N = in_sizes[0] / F_IN;        // 100000
    const int E = in_sizes[1] / 2;           // 1280000
    const int* src = ei;
    const int* dst = ei + E;

    // ---- workspace layout (256B-aligned slabs) ----
    char* base = (char*)d_ws;
    size_t off = 0;
    auto alloc = [&](size_t bytes) {
        char* p = base + off;
        off = (off + bytes + 255) & ~(size_t)255;
        return p;
    };
    int*   deg_i  = (int*)  alloc((size_t)N * 4);
    int*   dhist  = (int*)  alloc((size_t)NBIN * 4);   // adjacent to deg_i conceptually
    float* dinv   = (float*)alloc((size_t)N * 4);
    float* dinv2  = (float*)alloc((size_t)N * 4);
    int*   rowptr = (int*)  alloc((size_t)(N + 1) * 4);
    int*   cursor = (int*)  alloc((size_t)N * 4);
    int*   bsum   = (int*)  alloc(256 * 4);
    int*   bincur = (int*)  alloc((size_t)NBIN * 4);
    int*   perm   = (int*)  alloc((size_t)N * 4);
    int*   srcs_s = (int*)  alloc((size_t)E * 4);
    float* uA     = (float*)alloc((size_t)N * F_OUT * 4);
    float* uB     = (float*)d_out;           // d_out doubles as ping-pong buffer

    const int nb = (N + SCAN_TILE - 1) / SCAN_TILE;   // 98 blocks

    // 1) degrees, dinv/dinv2, degree histogram
    hipMemsetAsync(deg_i, 0, (size_t)N * sizeof(int), stream);
    hipMemsetAsync(dhist, 0, (size_t)NBIN * sizeof(int), stream);
    deg_count_kernel<<<(E + 255) / 256, 256, 0, stream>>>(dst, E, deg_i);
    dinv_kernel<<<(N + 255) / 256, 256, 0, stream>>>(deg_i, dinv, dinv2, dhist, N);

    // 2) rowptr scan + degree-sorted permutation
    scan_a_kernel<<<nb, SCAN_BLK, 0, stream>>>(deg_i, bsum, N);
    scan_b_kernel<<<1, 256, 0, stream>>>(bsum, rowptr + N, nb);
    scan_c_kernel<<<nb, SCAN_BLK, 0, stream>>>(deg_i, bsum, rowptr, cursor, N);
    binscan_kernel<<<1, NBIN, 0, stream>>>(dhist, bincur);
    perm_kernel<<<(N + 255) / 256, 256, 0, stream>>>(deg_i, bincur, perm, N);

    // 3) edge reorder (4B records)
    reorder_kernel<<<(E + 255) / 256, 256, 0, stream>>>(src, dst, cursor, srcs_s, E);

    // 4) projection u0 = dinv * (x @ W^T)
    proj_kernel<<<(N + 255) / 256, 256, 0, stream>>>(x, W, dinv, uA, N);

    // 5) three pull hops in u-space: uA -> uB -> uA -> uB
    const int pt = N * F4;                   // 1M threads
    const int pg = (pt + 255) / 256;
    propagate_kernel<<<pg, 256, 0, stream>>>(perm, rowptr, srcs_s, dinv2, uA, uB, N);
    propagate_kernel<<<pg, 256, 0, stream>>>(perm, rowptr, srcs_s, dinv2, uB, uA, N);
    propagate_kernel<<<pg, 256, 0, stream>>>(perm, rowptr, srcs_s, dinv2, uA, uB, N);

    // 6) y3 = D^{1/2} u3, + bias, log_softmax in place on d_out
    logsoftmax_kernel<<<(N + 255) / 256, 256, 0, stream>>>(uB, b, deg_i, N);
}

// Round 5
// 413.772 us; speedup vs baseline: 2.5226x; 2.5226x over previous
//
#include <hip/hip_runtime.h>

#define F_IN 64
#define F_OUT 40
#define F4 (F_OUT / 4)        // 10 float4 per row

#define SCAN_BLK 256
#define SCAN_ELEMS 4
#define SCAN_TILE (SCAN_BLK * SCAN_ELEMS)   // 1024 elems per block

// ---------------- degree histogram (int) ----------------
__global__ void deg_count_kernel(const int* __restrict__ dst, int E, int* __restrict__ deg) {
    int e = blockIdx.x * blockDim.x + threadIdx.x;
    if (e < E) atomicAdd(&deg[dst[e]], 1);
}

// dinv = rsqrt(deg+1), dinv2 = dinv^2
__global__ void dinv_kernel(const int* __restrict__ deg, float* __restrict__ dinv,
                            float* __restrict__ dinv2, int n) {
    int i = blockIdx.x * blockDim.x + threadIdx.x;
    if (i >= n) return;
    float r = rsqrtf((float)deg[i] + 1.0f);
    dinv[i] = r;
    dinv2[i] = r * r;
}

// ---------------- hierarchical scan: A) per-block reduce ----------------
__global__ __launch_bounds__(SCAN_BLK) void scan_a_kernel(const int* __restrict__ deg,
                                                          int* __restrict__ bsum, int n) {
    __shared__ int s[SCAN_BLK];
    int tid = threadIdx.x;
    int base = blockIdx.x * SCAN_TILE + tid * SCAN_ELEMS;
    int local = 0;
#pragma unroll
    for (int k = 0; k < SCAN_ELEMS; ++k) {
        int i = base + k;
        if (i < n) local += deg[i];
    }
    s[tid] = local;
    __syncthreads();
    for (int off = SCAN_BLK / 2; off > 0; off >>= 1) {
        if (tid < off) s[tid] += s[tid + off];
        __syncthreads();
    }
    if (tid == 0) bsum[blockIdx.x] = s[0];
}

// ---------------- B) single-block scan of <=256 partials ----------------
__global__ __launch_bounds__(256) void scan_b_kernel(int* __restrict__ bsum,
                                                     int* __restrict__ total_out, int nb) {
    __shared__ int s[256];
    int tid = threadIdx.x;
    int v = (tid < nb) ? bsum[tid] : 0;
    s[tid] = v;
    __syncthreads();
    for (int off = 1; off < 256; off <<= 1) {
        int t = (tid >= off) ? s[tid - off] : 0;
        __syncthreads();
        s[tid] += t;
        __syncthreads();
    }
    if (tid < nb) bsum[tid] = s[tid] - v;     // exclusive block offset
    if (tid == 255) *total_out = s[255];      // rowptr[n]
}

// ---------------- C) per-block local scan + offset -> rowptr & cursor ----------------
__global__ __launch_bounds__(SCAN_BLK) void scan_c_kernel(const int* __restrict__ deg,
                                                          const int* __restrict__ boff,
                                                          int* __restrict__ rowptr,
                                                          int* __restrict__ cursor, int n) {
    __shared__ int s[SCAN_BLK];
    int tid = threadIdx.x;
    int base = blockIdx.x * SCAN_TILE + tid * SCAN_ELEMS;
    int vals[SCAN_ELEMS];
    int local = 0;
#pragma unroll
    for (int k = 0; k < SCAN_ELEMS; ++k) {
        int i = base + k;
        vals[k] = (i < n) ? deg[i] : 0;
        local += vals[k];
    }
    s[tid] = local;
    __syncthreads();
    for (int off = 1; off < SCAN_BLK; off <<= 1) {
        int t = (tid >= off) ? s[tid - off] : 0;
        __syncthreads();
        s[tid] += t;
        __syncthreads();
    }
    int prefix = boff[blockIdx.x] + s[tid] - local;
#pragma unroll
    for (int k = 0; k < SCAN_ELEMS; ++k) {
        int i = base + k;
        if (i < n) {
            rowptr[i] = prefix;
            cursor[i] = prefix;
            prefix += vals[k];
        }
    }
}

// ---------------- reorder edges by dst: record = src index only (4B) ----------------
__global__ void reorder_kernel(const int* __restrict__ src, const int* __restrict__ dst,
                               int* __restrict__ cursor, int* __restrict__ srcs_sorted, int E) {
    int e = blockIdx.x * blockDim.x + threadIdx.x;
    if (e >= E) return;
    int r = src[e];
    int c = dst[e];
    int pos = atomicAdd(&cursor[c], 1);
    srcs_sorted[pos] = r;
}

// ---------------- projection u0 = dinv * (x @ W^T) ----------------
__global__ __launch_bounds__(256) void proj_kernel(const float* __restrict__ x,
                                                   const float* __restrict__ W,
                                                   const float* __restrict__ dinv,
                                                   float* __restrict__ u, int n) {
    __shared__ float Ws[F_OUT * F_IN];
    for (int i = threadIdx.x; i < F_OUT * F_IN; i += blockDim.x) Ws[i] = W[i];
    __syncthreads();

    int node = blockIdx.x * blockDim.x + threadIdx.x;
    if (node >= n) return;

    const float4* xp  = (const float4*)(x + (size_t)node * F_IN);
    const float4* Ws4 = (const float4*)Ws;

    float acc[F_OUT];
#pragma unroll
    for (int c = 0; c < F_OUT; ++c) acc[c] = 0.0f;

#pragma unroll
    for (int f4 = 0; f4 < F_IN / 4; ++f4) {
        float4 xv = xp[f4];
#pragma unroll
        for (int c = 0; c < F_OUT; ++c) {
            float4 w = Ws4[c * (F_IN / 4) + f4];
            acc[c] += xv.x * w.x + xv.y * w.y + xv.z * w.z + xv.w * w.w;
        }
    }

    float dv = dinv[node];
    float4* up = (float4*)(u + (size_t)node * F_OUT);
#pragma unroll
    for (int c4 = 0; c4 < F4; ++c4) {
        float4 v;
        v.x = dv * acc[4 * c4 + 0]; v.y = dv * acc[4 * c4 + 1];
        v.z = dv * acc[4 * c4 + 2]; v.w = dv * acc[4 * c4 + 3];
        up[c4] = v;
    }
}

// ---------------- pull propagation in u-space: u' = dinv2 * ((A u) + u) ----------------
// thread t handles (node = t/10, f4 = t%10): one float4 of the output row.
__global__ __launch_bounds__(256) void propagate_kernel(const int* __restrict__ rowptr,
                                                        const int* __restrict__ srcs,
                                                        const float* __restrict__ dinv2,
                                                        const float* __restrict__ ucur,
                                                        float* __restrict__ unew, int n) {
    int t = blockIdx.x * blockDim.x + threadIdx.x;
    int node = t / F4;
    int f4 = t - node * F4;
    if (node >= n) return;

    int beg = rowptr[node];
    int end = rowptr[node + 1];

    const float4* u4 = (const float4*)ucur;
    // self loop term
    float4 acc = u4[(size_t)node * F4 + f4];

    int i = beg;
    for (; i + 3 < end; i += 4) {          // unroll x4: batch index loads, then gathers
        int s0 = srcs[i];
        int s1 = srcs[i + 1];
        int s2 = srcs[i + 2];
        int s3 = srcs[i + 3];
        float4 v0 = u4[(size_t)s0 * F4 + f4];
        float4 v1 = u4[(size_t)s1 * F4 + f4];
        float4 v2 = u4[(size_t)s2 * F4 + f4];
        float4 v3 = u4[(size_t)s3 * F4 + f4];
        acc.x += v0.x + v1.x + v2.x + v3.x;
        acc.y += v0.y + v1.y + v2.y + v3.y;
        acc.z += v0.z + v1.z + v2.z + v3.z;
        acc.w += v0.w + v1.w + v2.w + v3.w;
    }
    for (; i < end; ++i) {
        float4 v = u4[(size_t)srcs[i] * F4 + f4];
        acc.x += v.x; acc.y += v.y; acc.z += v.z; acc.w += v.w;
    }

    float ds = dinv2[node];
    acc.x *= ds; acc.y *= ds; acc.z *= ds; acc.w *= ds;
    ((float4*)unew)[(size_t)node * F4 + f4] = acc;
}

// ---------------- bias + log_softmax, with final y = D^{1/2} u scale ----------------
__global__ void logsoftmax_kernel(float* __restrict__ out, const float* __restrict__ bias,
                                  const int* __restrict__ deg, int n) {
    int node = blockIdx.x * blockDim.x + threadIdx.x;
    if (node >= n) return;
    float sq = sqrtf((float)deg[node] + 1.0f);   // 1/dinv
    float4* p = (float4*)(out + (size_t)node * F_OUT);
    float v[F_OUT];
#pragma unroll
    for (int c4 = 0; c4 < F4; ++c4) {
        float4 t = p[c4];
        v[4 * c4 + 0] = sq * t.x + bias[4 * c4 + 0];
        v[4 * c4 + 1] = sq * t.y + bias[4 * c4 + 1];
        v[4 * c4 + 2] = sq * t.z + bias[4 * c4 + 2];
        v[4 * c4 + 3] = sq * t.w + bias[4 * c4 + 3];
    }
    float mx = -1e30f;
#pragma unroll
    for (int c = 0; c < F_OUT; ++c) mx = fmaxf(mx, v[c]);
    float se = 0.0f;
#pragma unroll
    for (int c = 0; c < F_OUT; ++c) se += __expf(v[c] - mx);
    float lse = mx + __logf(se);
#pragma unroll
    for (int c4 = 0; c4 < F4; ++c4) {
        float4 t;
        t.x = v[4 * c4 + 0] - lse; t.y = v[4 * c4 + 1] - lse;
        t.z = v[4 * c4 + 2] - lse; t.w = v[4 * c4 + 3] - lse;
        p[c4] = t;
    }
}

extern "C" void kernel_launch(void* const* d_in, const int* in_sizes, int n_in,
                              void* d_out, int out_size, void* d_ws, size_t ws_size,
                              hipStream_t stream) {
    const float* x  = (const float*)d_in[0];
    const int*   ei = (const int*)d_in[1];
    const float* W  = (const float*)d_in[2];
    const float* b  = (const float*)d_in[3];

    const int N = in_sizes[0] / F_IN;        // 100000
    const int E = in_sizes[1] / 2;           // 1280000
    const int* src = ei;
    const int* dst = ei + E;

    // ---- workspace layout (256B-aligned slabs) ----
    char* base = (char*)d_ws;
    size_t off = 0;
    auto alloc = [&](size_t bytes) {
        char* p = base + off;
        off = (off + bytes + 255) & ~(size_t)255;
        return p;
    };
    int*   deg_i  = (int*)  alloc((size_t)N * 4);
    float* dinv   = (float*)alloc((size_t)N * 4);
    float* dinv2  = (float*)alloc((size_t)N * 4);
    int*   rowptr = (int*)  alloc((size_t)(N + 1) * 4);
    int*   cursor = (int*)  alloc((size_t)N * 4);
    int*   bsum   = (int*)  alloc(256 * 4);
    int*   srcs_s = (int*)  alloc((size_t)E * 4);
    float* uA     = (float*)alloc((size_t)N * F_OUT * 4);
    float* uB     = (float*)d_out;           // d_out doubles as ping-pong buffer

    const int nb = (N + SCAN_TILE - 1) / SCAN_TILE;   // 98 blocks

    // 1) degrees, dinv/dinv2
    hipMemsetAsync(deg_i, 0, (size_t)N * sizeof(int), stream);
    deg_count_kernel<<<(E + 255) / 256, 256, 0, stream>>>(dst, E, deg_i);
    dinv_kernel<<<(N + 255) / 256, 256, 0, stream>>>(deg_i, dinv, dinv2, N);

    // 2) rowptr scan
    scan_a_kernel<<<nb, SCAN_BLK, 0, stream>>>(deg_i, bsum, N);
    scan_b_kernel<<<1, 256, 0, stream>>>(bsum, rowptr + N, nb);
    scan_c_kernel<<<nb, SCAN_BLK, 0, stream>>>(deg_i, bsum, rowptr, cursor, N);

    // 3) edge reorder (4B records)
    reorder_kernel<<<(E + 255) / 256, 256, 0, stream>>>(src, dst, cursor, srcs_s, E);

    // 4) projection u0 = dinv * (x @ W^T)
    proj_kernel<<<(N + 255) / 256, 256, 0, stream>>>(x, W, dinv, uA, N);

    // 5) three pull hops in u-space: uA -> uB -> uA -> uB
    const int pt = N * F4;                   // 1M threads
    const int pg = (pt + 255) / 256;
    propagate_kernel<<<pg, 256, 0, stream>>>(rowptr, srcs_s, dinv2, uA, uB, N);
    propagate_kernel<<<pg, 256, 0, stream>>>(rowptr, srcs_s, dinv2, uB, uA, N);
    propagate_kernel<<<pg, 256, 0, stream>>>(rowptr, srcs_s, dinv2, uA, uB, N);

    // 6) y3 = D^{1/2} u3, + bias, log_softmax in place on d_out
    logsoftmax_kernel<<<(N + 255) / 256, 256, 0, stream>>>(uB, b, deg_i, N);
}

// Round 6
// 323.058 us; speedup vs baseline: 3.2309x; 1.2808x over previous
//
#include <hip/hip_runtime.h>

#define F_IN 64
#define F_OUT 40
#define F4 10            // float4 chunks per fp32 row
#define USTRIDE 20       // uint32 per bf16 row (40 bf16 = 80 B)

#define SCAN_BLK 256
#define SCAN_ELEMS 4
#define SCAN_TILE (SCAN_BLK * SCAN_ELEMS)   // 1024

#define PART_BLK 256
#define PART_EPB 16
#define PART_TILE (PART_BLK * PART_EPB)     // 4096 edges per partition block
#define BSHIFT 8                            // 256 nodes per bucket
#define MAXB 400                            // >= ceil(100000/256)+1 = 392

// ---- bf16 helpers (round-to-nearest-even, pack 2 per uint) ----
__device__ inline unsigned pk2(float x, float y) {
    unsigned a = __float_as_uint(x); a = (a + 0x7FFFu + ((a >> 16) & 1u)) >> 16;
    unsigned b = __float_as_uint(y); b = (b + 0x7FFFu + ((b >> 16) & 1u)) >> 16;
    return a | (b << 16);
}
__device__ inline void up4(uint2 u, float& a, float& b, float& c, float& d) {
    a = __uint_as_float(u.x << 16); b = __uint_as_float(u.x & 0xFFFF0000u);
    c = __uint_as_float(u.y << 16); d = __uint_as_float(u.y & 0xFFFF0000u);
}

// ---------------- degree histogram ----------------
__global__ void deg_count_kernel(const int* __restrict__ dst, int E, int* __restrict__ deg) {
    int e = blockIdx.x * blockDim.x + threadIdx.x;
    if (e < E) atomicAdd(&deg[dst[e]], 1);
}

__global__ void dinv_kernel(const int* __restrict__ deg, float* __restrict__ dinv,
                            float* __restrict__ dinv2, int n) {
    int i = blockIdx.x * blockDim.x + threadIdx.x;
    if (i >= n) return;
    float r = rsqrtf((float)deg[i] + 1.0f);
    dinv[i] = r;
    dinv2[i] = r * r;
}

// ---------------- hierarchical scan ----------------
__global__ __launch_bounds__(SCAN_BLK) void scan_a_kernel(const int* __restrict__ deg,
                                                          int* __restrict__ bsum, int n) {
    __shared__ int s[SCAN_BLK];
    int tid = threadIdx.x;
    int base = blockIdx.x * SCAN_TILE + tid * SCAN_ELEMS;
    int local = 0;
#pragma unroll
    for (int k = 0; k < SCAN_ELEMS; ++k) {
        int i = base + k;
        if (i < n) local += deg[i];
    }
    s[tid] = local;
    __syncthreads();
    for (int off = SCAN_BLK / 2; off > 0; off >>= 1) {
        if (tid < off) s[tid] += s[tid + off];
        __syncthreads();
    }
    if (tid == 0) bsum[blockIdx.x] = s[0];
}

__global__ __launch_bounds__(256) void scan_b_kernel(int* __restrict__ bsum,
                                                     int* __restrict__ total_out, int nb) {
    __shared__ int s[256];
    int tid = threadIdx.x;
    int v = (tid < nb) ? bsum[tid] : 0;
    s[tid] = v;
    __syncthreads();
    for (int off = 1; off < 256; off <<= 1) {
        int t = (tid >= off) ? s[tid - off] : 0;
        __syncthreads();
        s[tid] += t;
        __syncthreads();
    }
    if (tid < nb) bsum[tid] = s[tid] - v;
    if (tid == 255) *total_out = s[255];
}

__global__ __launch_bounds__(SCAN_BLK) void scan_c_kernel(const int* __restrict__ deg,
                                                          const int* __restrict__ boff,
                                                          int* __restrict__ rowptr,
                                                          int* __restrict__ cursor, int n) {
    __shared__ int s[SCAN_BLK];
    int tid = threadIdx.x;
    int base = blockIdx.x * SCAN_TILE + tid * SCAN_ELEMS;
    int vals[SCAN_ELEMS];
    int local = 0;
#pragma unroll
    for (int k = 0; k < SCAN_ELEMS; ++k) {
        int i = base + k;
        vals[k] = (i < n) ? deg[i] : 0;
        local += vals[k];
    }
    s[tid] = local;
    __syncthreads();
    for (int off = 1; off < SCAN_BLK; off <<= 1) {
        int t = (tid >= off) ? s[tid - off] : 0;
        __syncthreads();
        s[tid] += t;
        __syncthreads();
    }
    int prefix = boff[blockIdx.x] + s[tid] - local;
#pragma unroll
    for (int k = 0; k < SCAN_ELEMS; ++k) {
        int i = base + k;
        if (i < n) {
            rowptr[i] = prefix;
            cursor[i] = prefix;
            prefix += vals[k];
        }
    }
}

// ---------------- bucket fill cursors start at rowptr[b<<8] ----------------
__global__ void bucket_init_kernel(const int* __restrict__ rowptr, int* __restrict__ bfill,
                                   int nbk, int n) {
    int b = blockIdx.x * blockDim.x + threadIdx.x;
    if (b < nbk) bfill[b] = rowptr[min(b << BSHIFT, n)];
}

// ---------------- phase A: multisplit partition into 391 dst-buckets ----------------
// record: src (17b) | (dst&255)<<17 — 4 B. Writes are per-(block,bucket) contiguous runs.
__global__ __launch_bounds__(PART_BLK) void partition_kernel(const int* __restrict__ src,
                                                             const int* __restrict__ dst,
                                                             int* __restrict__ bfill,
                                                             unsigned* __restrict__ staging,
                                                             int E, int nbk) {
    __shared__ int hist[MAXB];
    __shared__ int base[MAXB];
    int tid = threadIdx.x;
    for (int b = tid; b < nbk; b += PART_BLK) hist[b] = 0;
    __syncthreads();

    int rank[PART_EPB];
    int bk[PART_EPB];
    unsigned rec[PART_EPB];
    int eb = blockIdx.x * PART_TILE + tid;
#pragma unroll
    for (int k = 0; k < PART_EPB; ++k) {
        int e = eb + k * PART_BLK;
        if (e < E) {
            int r = src[e];
            int c = dst[e];
            int b = c >> BSHIFT;
            bk[k] = b;
            rec[k] = (unsigned)r | ((unsigned)(c & 255) << 17);
            rank[k] = atomicAdd(&hist[b], 1);
        } else {
            bk[k] = -1;
        }
    }
    __syncthreads();
    for (int b = tid; b < nbk; b += PART_BLK) {
        int h = hist[b];
        base[b] = h ? atomicAdd(&bfill[b], h) : 0;
    }
    __syncthreads();
#pragma unroll
    for (int k = 0; k < PART_EPB; ++k) {
        if (bk[k] >= 0) staging[base[bk[k]] + rank[k]] = rec[k];
    }
}

// ---------------- phase B: fine scatter within buckets ----------------
__global__ __launch_bounds__(256) void scatter_fine_kernel(const unsigned* __restrict__ staging,
                                                           const int* __restrict__ rowptr,
                                                           int* __restrict__ cursor,
                                                           int* __restrict__ srcs, int E,
                                                           int nbk, int n) {
    __shared__ int bb[MAXB];
    int tid = threadIdx.x;
    for (int b = tid; b <= nbk; b += 256) bb[b] = rowptr[min(b << BSHIFT, n)];
    __syncthreads();
    int i = blockIdx.x * 256 + tid;
    if (i >= E) return;
    unsigned rec = staging[i];
    int lo = 0, hi = nbk;                 // invariant: bb[lo] <= i < bb[hi]
    while (hi - lo > 1) {
        int mid = (lo + hi) >> 1;
        if (bb[mid] <= i) lo = mid; else hi = mid;
    }
    int c = (lo << BSHIFT) | (int)(rec >> 17);
    int r = (int)(rec & 0x1FFFFu);
    int pos = atomicAdd(&cursor[c], 1);
    srcs[pos] = r;
}

// ---------------- projection u0 = dinv * (x @ W^T), bf16 out ----------------
__global__ __launch_bounds__(256) void proj_kernel(const float* __restrict__ x,
                                                   const float* __restrict__ W,
                                                   const float* __restrict__ dinv,
                                                   unsigned* __restrict__ u, int n) {
    __shared__ float Ws[F_OUT * F_IN];
    for (int i = threadIdx.x; i < F_OUT * F_IN; i += blockDim.x) Ws[i] = W[i];
    __syncthreads();

    int node = blockIdx.x * blockDim.x + threadIdx.x;
    if (node >= n) return;

    const float4* xp  = (const float4*)(x + (size_t)node * F_IN);
    const float4* Ws4 = (const float4*)Ws;

    float acc[F_OUT];
#pragma unroll
    for (int c = 0; c < F_OUT; ++c) acc[c] = 0.0f;
#pragma unroll
    for (int f4 = 0; f4 < F_IN / 4; ++f4) {
        float4 xv = xp[f4];
#pragma unroll
        for (int c = 0; c < F_OUT; ++c) {
            float4 w = Ws4[c * (F_IN / 4) + f4];
            acc[c] += xv.x * w.x + xv.y * w.y + xv.z * w.z + xv.w * w.w;
        }
    }
    float dv = dinv[node];
    uint4* up = (uint4*)(u + (size_t)node * USTRIDE);   // 80 B row, 16 B aligned
#pragma unroll
    for (int g = 0; g < 5; ++g) {                       // 5 uint4 = 8 bf16 each
        uint4 o;
        o.x = pk2(dv * acc[8 * g + 0], dv * acc[8 * g + 1]);
        o.y = pk2(dv * acc[8 * g + 2], dv * acc[8 * g + 3]);
        o.z = pk2(dv * acc[8 * g + 4], dv * acc[8 * g + 5]);
        o.w = pk2(dv * acc[8 * g + 6], dv * acc[8 * g + 7]);
        up[g] = o;
    }
}

// ---------------- pull propagation in u-space (bf16 rows, fp32 accum) ----------------
// thread t: node = t/10, q = t%10 handles one uint2 (4 bf16) of the row.
__global__ __launch_bounds__(256) void propagate_kernel(const int* __restrict__ rowptr,
                                                        const int* __restrict__ srcs,
                                                        const float* __restrict__ dinv2,
                                                        const unsigned* __restrict__ ucur,
                                                        unsigned* __restrict__ unew, int n) {
    int t = blockIdx.x * blockDim.x + threadIdx.x;
    int node = t / F4;
    int q = t - node * F4;
    if (node >= n) return;

    int beg = rowptr[node];
    int end = rowptr[node + 1];

    const uint2* U = (const uint2*)ucur;
    float ax, ay, az, aw;
    up4(U[(size_t)node * F4 + q], ax, ay, az, aw);      // self loop

    int i = beg;
    for (; i + 3 < end; i += 4) {
        int s0 = srcs[i], s1 = srcs[i + 1], s2 = srcs[i + 2], s3 = srcs[i + 3];
        uint2 v0 = U[(size_t)s0 * F4 + q];
        uint2 v1 = U[(size_t)s1 * F4 + q];
        uint2 v2 = U[(size_t)s2 * F4 + q];
        uint2 v3 = U[(size_t)s3 * F4 + q];
        float b0, b1, b2, b3;
        up4(v0, b0, b1, b2, b3); ax += b0; ay += b1; az += b2; aw += b3;
        up4(v1, b0, b1, b2, b3); ax += b0; ay += b1; az += b2; aw += b3;
        up4(v2, b0, b1, b2, b3); ax += b0; ay += b1; az += b2; aw += b3;
        up4(v3, b0, b1, b2, b3); ax += b0; ay += b1; az += b2; aw += b3;
    }
    for (; i < end; ++i) {
        float b0, b1, b2, b3;
        up4(U[(size_t)srcs[i] * F4 + q], b0, b1, b2, b3);
        ax += b0; ay += b1; az += b2; aw += b3;
    }

    float ds = dinv2[node];
    uint2 o;
    o.x = pk2(ds * ax, ds * ay);
    o.y = pk2(ds * az, ds * aw);
    ((uint2*)unew)[(size_t)node * F4 + q] = o;
}

// ---------------- y = D^{1/2} u3 + bias, log_softmax -> fp32 d_out ----------------
__global__ void logsoftmax_kernel(const unsigned* __restrict__ u, float* __restrict__ out,
                                  const float* __restrict__ bias,
                                  const int* __restrict__ deg, int n) {
    int node = blockIdx.x * blockDim.x + threadIdx.x;
    if (node >= n) return;
    float sq = sqrtf((float)deg[node] + 1.0f);
    const uint4* up = (const uint4*)(u + (size_t)node * USTRIDE);
    float v[F_OUT];
#pragma unroll
    for (int g = 0; g < 5; ++g) {
        uint4 t = up[g];
        float a, b, c, d;
        up4(make_uint2(t.x, t.y), a, b, c, d);
        v[8 * g + 0] = sq * a + bias[8 * g + 0];
        v[8 * g + 1] = sq * b + bias[8 * g + 1];
        v[8 * g + 2] = sq * c + bias[8 * g + 2];
        v[8 * g + 3] = sq * d + bias[8 * g + 3];
        up4(make_uint2(t.z, t.w), a, b, c, d);
        v[8 * g + 4] = sq * a + bias[8 * g + 4];
        v[8 * g + 5] = sq * b + bias[8 * g + 5];
        v[8 * g + 6] = sq * c + bias[8 * g + 6];
        v[8 * g + 7] = sq * d + bias[8 * g + 7];
    }
    float mx = -1e30f;
#pragma unroll
    for (int c = 0; c < F_OUT; ++c) mx = fmaxf(mx, v[c]);
    float se = 0.0f;
#pragma unroll
    for (int c = 0; c < F_OUT; ++c) se += __expf(v[c] - mx);
    float lse = mx + __logf(se);
    float4* p = (float4*)(out + (size_t)node * F_OUT);
#pragma unroll
    for (int c4 = 0; c4 < F4; ++c4) {
        float4 t;
        t.x = v[4 * c4 + 0] - lse; t.y = v[4 * c4 + 1] - lse;
        t.z = v[4 * c4 + 2] - lse; t.w = v[4 * c4 + 3] - lse;
        p[c4] = t;
    }
}

extern "C" void kernel_launch(void* const* d_in, const int* in_sizes, int n_in,
                              void* d_out, int out_size, void* d_ws, size_t ws_size,
                              hipStream_t stream) {
    const float* x  = (const float*)d_in[0];
    const int*   ei = (const int*)d_in[1];
    const float* W  = (const float*)d_in[2];
    const float* b  = (const float*)d_in[3];

    const int N = in_sizes[0] / F_IN;        // 100000
    const int E = in_sizes[1] / 2;           // 1280000
    const int* src = ei;
    const int* dst = ei + E;
    const int nbk = (N + (1 << BSHIFT) - 1) >> BSHIFT;   // 391

    // ---- workspace layout ----
    char* base = (char*)d_ws;
    size_t off = 0;
    auto alloc = [&](size_t bytes) {
        char* p = base + off;
        off = (off + bytes + 255) & ~(size_t)255;
        return p;
    };
    int*      deg_i   = (int*)     alloc((size_t)N * 4);
    float*    dinv    = (float*)   alloc((size_t)N * 4);
    float*    dinv2   = (float*)   alloc((size_t)N * 4);
    int*      rowptr  = (int*)     alloc((size_t)(N + 1) * 4);
    int*      cursor  = (int*)     alloc((size_t)N * 4);
    int*      bsum    = (int*)     alloc(256 * 4);
    int*      bfill   = (int*)     alloc((size_t)MAXB * 4);
    unsigned* staging = (unsigned*)alloc((size_t)E * 4);
    int*      srcs_s  = (int*)     alloc((size_t)E * 4);
    unsigned* uA      = (unsigned*)alloc((size_t)N * USTRIDE * 4);   // 8 MB
    unsigned* uB      = (unsigned*)alloc((size_t)N * USTRIDE * 4);   // 8 MB
    float*    outp    = (float*)d_out;

    const int nb = (N + SCAN_TILE - 1) / SCAN_TILE;   // 98

    // 1) degrees, dinv/dinv2
    hipMemsetAsync(deg_i, 0, (size_t)N * sizeof(int), stream);
    deg_count_kernel<<<(E + 255) / 256, 256, 0, stream>>>(dst, E, deg_i);
    dinv_kernel<<<(N + 255) / 256, 256, 0, stream>>>(deg_i, dinv, dinv2, N);

    // 2) rowptr scan (+ cursor copy)
    scan_a_kernel<<<nb, SCAN_BLK, 0, stream>>>(deg_i, bsum, N);
    scan_b_kernel<<<1, 256, 0, stream>>>(bsum, rowptr + N, nb);
    scan_c_kernel<<<nb, SCAN_BLK, 0, stream>>>(deg_i, bsum, rowptr, cursor, N);

    // 3) two-phase edge reorder
    bucket_init_kernel<<<(nbk + 255) / 256, 256, 0, stream>>>(rowptr, bfill, nbk, N);
    partition_kernel<<<(E + PART_TILE - 1) / PART_TILE, PART_BLK, 0, stream>>>(
        src, dst, bfill, staging, E, nbk);
    scatter_fine_kernel<<<(E + 255) / 256, 256, 0, stream>>>(staging, rowptr, cursor,
                                                             srcs_s, E, nbk, N);

    // 4) projection u0 = dinv * (x @ W^T) -> bf16 uA
    proj_kernel<<<(N + 255) / 256, 256, 0, stream>>>(x, W, dinv, uA, N);

    // 5) three pull hops in bf16 u-space: uA -> uB -> uA -> uB
    const int pt = N * F4;
    const int pg = (pt + 255) / 256;
    propagate_kernel<<<pg, 256, 0, stream>>>(rowptr, srcs_s, dinv2, uA, uB, N);
    propagate_kernel<<<pg, 256, 0, stream>>>(rowptr, srcs_s, dinv2, uB, uA, N);
    propagate_kernel<<<pg, 256, 0, stream>>>(rowptr, srcs_s, dinv2, uA, uB, N);

    // 6) y3 = D^{1/2} u3 + bias, log_softmax -> d_out (fp32)
    logsoftmax_kernel<<<(N + 255) / 256, 256, 0, stream>>>(uB, outp, b, deg_i, N);
}

// Round 7
// 247.353 us; speedup vs baseline: 4.2197x; 1.3061x over previous
//
#include <hip/hip_runtime.h>

#define F_IN 64
#define F_OUT 40
#define F4 10            // uint2 (4 bf16) chunks per row
#define USTRIDE 20       // uint32 per bf16 row (40 bf16 = 80 B)

#define SCAN_BLK 256
#define SCAN_ELEMS 4
#define SCAN_TILE (SCAN_BLK * SCAN_ELEMS)   // 1024

#define PART_BLK 256
#define PART_EPB 16
#define PART_TILE (PART_BLK * PART_EPB)     // 4096 edges per partition block
#define BSHIFT 8                            // 256 nodes per bucket
#define BCAP 4096                           // staging slots per bucket (mean 3273, +14 sigma)
#define MAXB 400                            // >= ceil(100000/256) = 391

// ---- bf16 helpers (round-to-nearest-even, pack 2 per uint) ----
__device__ inline unsigned pk2(float x, float y) {
    unsigned a = __float_as_uint(x); a = (a + 0x7FFFu + ((a >> 16) & 1u)) >> 16;
    unsigned b = __float_as_uint(y); b = (b + 0x7FFFu + ((b >> 16) & 1u)) >> 16;
    return a | (b << 16);
}
__device__ inline void up4(uint2 u, float& a, float& b, float& c, float& d) {
    a = __uint_as_float(u.x << 16); b = __uint_as_float(u.x & 0xFFFF0000u);
    c = __uint_as_float(u.y << 16); d = __uint_as_float(u.y & 0xFFFF0000u);
}

// ---------------- phase A: multisplit partition into dst-buckets ----------------
// bucket b staging region: [b*BCAP, (b+1)*BCAP). record: src(17b) | dstLow(8b)<<17.
// Per-edge atomics are LDS-only; one global atomic per (block,bucket).
__global__ __launch_bounds__(PART_BLK) void partition_kernel(const int* __restrict__ src,
                                                             const int* __restrict__ dst,
                                                             int* __restrict__ bfill,
                                                             unsigned* __restrict__ staging,
                                                             int E, int nbk) {
    __shared__ int hist[MAXB];
    __shared__ int base[MAXB];
    int tid = threadIdx.x;
    for (int b = tid; b < nbk; b += PART_BLK) hist[b] = 0;
    __syncthreads();

    int rank[PART_EPB];
    int bk[PART_EPB];
    unsigned rec[PART_EPB];
    int eb = blockIdx.x * PART_TILE + tid;
#pragma unroll
    for (int k = 0; k < PART_EPB; ++k) {
        int e = eb + k * PART_BLK;
        if (e < E) {
            int r = src[e];
            int c = dst[e];
            int b = c >> BSHIFT;
            bk[k] = b;
            rec[k] = (unsigned)r | ((unsigned)(c & 255) << 17);
            rank[k] = atomicAdd(&hist[b], 1);
        } else {
            bk[k] = -1;
        }
    }
    __syncthreads();
    for (int b = tid; b < nbk; b += PART_BLK) {
        int h = hist[b];
        base[b] = h ? atomicAdd(&bfill[b], h) : 0;
    }
    __syncthreads();
#pragma unroll
    for (int k = 0; k < PART_EPB; ++k) {
        if (bk[k] >= 0) staging[base[bk[k]] + rank[k]] = rec[k];
    }
}

// ---------------- per-bucket degree count (LDS histogram, coalesced deg write) ----------------
__global__ __launch_bounds__(256) void bucket_deg_kernel(const unsigned* __restrict__ staging,
                                                         const int* __restrict__ bfill,
                                                         int* __restrict__ deg, int n) {
    int b = blockIdx.x;
    __shared__ int h[256];
    int tid = threadIdx.x;
    h[tid] = 0;
    __syncthreads();
    int cnt = bfill[b] - b * BCAP;
    const unsigned* rec = staging + (size_t)b * BCAP;
    for (int i = tid; i < cnt; i += 256) {
        atomicAdd(&h[rec[i] >> 17], 1);
    }
    __syncthreads();
    int node = (b << BSHIFT) | tid;
    if (node < n) deg[node] = h[tid];
}

__global__ void dinv_kernel(const int* __restrict__ deg, float* __restrict__ dinv,
                            float* __restrict__ dinv2, int n) {
    int i = blockIdx.x * blockDim.x + threadIdx.x;
    if (i >= n) return;
    float r = rsqrtf((float)deg[i] + 1.0f);
    dinv[i] = r;
    dinv2[i] = r * r;
}

// ---------------- hierarchical scan -> rowptr ----------------
__global__ __launch_bounds__(SCAN_BLK) void scan_a_kernel(const int* __restrict__ deg,
                                                          int* __restrict__ bsum, int n) {
    __shared__ int s[SCAN_BLK];
    int tid = threadIdx.x;
    int base = blockIdx.x * SCAN_TILE + tid * SCAN_ELEMS;
    int local = 0;
#pragma unroll
    for (int k = 0; k < SCAN_ELEMS; ++k) {
        int i = base + k;
        if (i < n) local += deg[i];
    }
    s[tid] = local;
    __syncthreads();
    for (int off = SCAN_BLK / 2; off > 0; off >>= 1) {
        if (tid < off) s[tid] += s[tid + off];
        __syncthreads();
    }
    if (tid == 0) bsum[blockIdx.x] = s[0];
}

__global__ __launch_bounds__(256) void scan_b_kernel(int* __restrict__ bsum,
                                                     int* __restrict__ total_out, int nb) {
    __shared__ int s[256];
    int tid = threadIdx.x;
    int v = (tid < nb) ? bsum[tid] : 0;
    s[tid] = v;
    __syncthreads();
    for (int off = 1; off < 256; off <<= 1) {
        int t = (tid >= off) ? s[tid - off] : 0;
        __syncthreads();
        s[tid] += t;
        __syncthreads();
    }
    if (tid < nb) bsum[tid] = s[tid] - v;
    if (tid == 255) *total_out = s[255];
}

__global__ __launch_bounds__(SCAN_BLK) void scan_c_kernel(const int* __restrict__ deg,
                                                          const int* __restrict__ boff,
                                                          int* __restrict__ rowptr, int n) {
    __shared__ int s[SCAN_BLK];
    int tid = threadIdx.x;
    int base = blockIdx.x * SCAN_TILE + tid * SCAN_ELEMS;
    int vals[SCAN_ELEMS];
    int local = 0;
#pragma unroll
    for (int k = 0; k < SCAN_ELEMS; ++k) {
        int i = base + k;
        vals[k] = (i < n) ? deg[i] : 0;
        local += vals[k];
    }
    s[tid] = local;
    __syncthreads();
    for (int off = 1; off < SCAN_BLK; off <<= 1) {
        int t = (tid >= off) ? s[tid - off] : 0;
        __syncthreads();
        s[tid] += t;
        __syncthreads();
    }
    int prefix = boff[blockIdx.x] + s[tid] - local;
#pragma unroll
    for (int k = 0; k < SCAN_ELEMS; ++k) {
        int i = base + k;
        if (i < n) {
            rowptr[i] = prefix;
            prefix += vals[k];
        }
    }
}

// ---------------- per-bucket fine scatter (LDS cursors, single-block bucket region) ------
__global__ __launch_bounds__(256) void bucket_scatter_kernel(const unsigned* __restrict__ staging,
                                                             const int* __restrict__ bfill,
                                                             const int* __restrict__ rowptr,
                                                             int* __restrict__ srcs, int n) {
    int b = blockIdx.x;
    __shared__ int cur[256];
    int tid = threadIdx.x;
    int node = (b << BSHIFT) | tid;
    cur[tid] = (node < n) ? rowptr[node] : 0;
    __syncthreads();
    int cnt = bfill[b] - b * BCAP;
    const unsigned* rec = staging + (size_t)b * BCAP;
    for (int i = tid; i < cnt; i += 256) {
        unsigned r = rec[i];
        int pos = atomicAdd(&cur[r >> 17], 1);
        srcs[pos] = (int)(r & 0x1FFFFu);
    }
}

// ---------------- projection u0 = dinv * (x @ W^T), bf16 out ----------------
__global__ __launch_bounds__(256) void proj_kernel(const float* __restrict__ x,
                                                   const float* __restrict__ W,
                                                   const float* __restrict__ dinv,
                                                   unsigned* __restrict__ u, int n) {
    __shared__ float Ws[F_OUT * F_IN];
    for (int i = threadIdx.x; i < F_OUT * F_IN; i += blockDim.x) Ws[i] = W[i];
    __syncthreads();

    int node = blockIdx.x * blockDim.x + threadIdx.x;
    if (node >= n) return;

    const float4* xp  = (const float4*)(x + (size_t)node * F_IN);
    const float4* Ws4 = (const float4*)Ws;

    float acc[F_OUT];
#pragma unroll
    for (int c = 0; c < F_OUT; ++c) acc[c] = 0.0f;
#pragma unroll
    for (int f4 = 0; f4 < F_IN / 4; ++f4) {
        float4 xv = xp[f4];
#pragma unroll
        for (int c = 0; c < F_OUT; ++c) {
            float4 w = Ws4[c * (F_IN / 4) + f4];
            acc[c] += xv.x * w.x + xv.y * w.y + xv.z * w.z + xv.w * w.w;
        }
    }
    float dv = dinv[node];
    uint4* up = (uint4*)(u + (size_t)node * USTRIDE);
#pragma unroll
    for (int g = 0; g < 5; ++g) {
        uint4 o;
        o.x = pk2(dv * acc[8 * g + 0], dv * acc[8 * g + 1]);
        o.y = pk2(dv * acc[8 * g + 2], dv * acc[8 * g + 3]);
        o.z = pk2(dv * acc[8 * g + 4], dv * acc[8 * g + 5]);
        o.w = pk2(dv * acc[8 * g + 6], dv * acc[8 * g + 7]);
        up[g] = o;
    }
}

// ---------------- pull propagation in u-space (bf16 rows, fp32 accum) ----------------
__global__ __launch_bounds__(256) void propagate_kernel(const int* __restrict__ rowptr,
                                                        const int* __restrict__ srcs,
                                                        const float* __restrict__ dinv2,
                                                        const unsigned* __restrict__ ucur,
                                                        unsigned* __restrict__ unew, int n) {
    int t = blockIdx.x * blockDim.x + threadIdx.x;
    int node = t / F4;
    int q = t - node * F4;
    if (node >= n) return;

    int beg = rowptr[node];
    int end = rowptr[node + 1];

    const uint2* U = (const uint2*)ucur;
    float ax, ay, az, aw;
    up4(U[(size_t)node * F4 + q], ax, ay, az, aw);      // self loop

    int i = beg;
    for (; i + 3 < end; i += 4) {
        int s0 = srcs[i], s1 = srcs[i + 1], s2 = srcs[i + 2], s3 = srcs[i + 3];
        uint2 v0 = U[(size_t)s0 * F4 + q];
        uint2 v1 = U[(size_t)s1 * F4 + q];
        uint2 v2 = U[(size_t)s2 * F4 + q];
        uint2 v3 = U[(size_t)s3 * F4 + q];
        float b0, b1, b2, b3;
        up4(v0, b0, b1, b2, b3); ax += b0; ay += b1; az += b2; aw += b3;
        up4(v1, b0, b1, b2, b3); ax += b0; ay += b1; az += b2; aw += b3;
        up4(v2, b0, b1, b2, b3); ax += b0; ay += b1; az += b2; aw += b3;
        up4(v3, b0, b1, b2, b3); ax += b0; ay += b1; az += b2; aw += b3;
    }
    for (; i < end; ++i) {
        float b0, b1, b2, b3;
        up4(U[(size_t)srcs[i] * F4 + q], b0, b1, b2, b3);
        ax += b0; ay += b1; az += b2; aw += b3;
    }

    float ds = dinv2[node];
    uint2 o;
    o.x = pk2(ds * ax, ds * ay);
    o.y = pk2(ds * az, ds * aw);
    ((uint2*)unew)[(size_t)node * F4 + q] = o;
}

// ---------------- y = D^{1/2} u3 + bias, log_softmax -> fp32 d_out ----------------
__global__ void logsoftmax_kernel(const unsigned* __restrict__ u, float* __restrict__ out,
                                  const float* __restrict__ bias,
                                  const int* __restrict__ deg, int n) {
    int node = blockIdx.x * blockDim.x + threadIdx.x;
    if (node >= n) return;
    float sq = sqrtf((float)deg[node] + 1.0f);
    const uint4* up = (const uint4*)(u + (size_t)node * USTRIDE);
    float v[F_OUT];
#pragma unroll
    for (int g = 0; g < 5; ++g) {
        uint4 t = up[g];
        float a, b, c, d;
        up4(make_uint2(t.x, t.y), a, b, c, d);
        v[8 * g + 0] = sq * a + bias[8 * g + 0];
        v[8 * g + 1] = sq * b + bias[8 * g + 1];
        v[8 * g + 2] = sq * c + bias[8 * g + 2];
        v[8 * g + 3] = sq * d + bias[8 * g + 3];
        up4(make_uint2(t.z, t.w), a, b, c, d);
        v[8 * g + 4] = sq * a + bias[8 * g + 4];
        v[8 * g + 5] = sq * b + bias[8 * g + 5];
        v[8 * g + 6] = sq * c + bias[8 * g + 6];
        v[8 * g + 7] = sq * d + bias[8 * g + 7];
    }
    float mx = -1e30f;
#pragma unroll
    for (int c = 0; c < F_OUT; ++c) mx = fmaxf(mx, v[c]);
    float se = 0.0f;
#pragma unroll
    for (int c = 0; c < F_OUT; ++c) se += __expf(v[c] - mx);
    float lse = mx + __logf(se);
    float4* p = (float4*)(out + (size_t)node * F_OUT);
#pragma unroll
    for (int c4 = 0; c4 < F4; ++c4) {
        float4 t;
        t.x = v[4 * c4 + 0] - lse; t.y = v[4 * c4 + 1] - lse;
        t.z = v[4 * c4 + 2] - lse; t.w = v[4 * c4 + 3] - lse;
        p[c4] = t;
    }
}

// ---------------- bucket fill cursors start at fixed slots b*BCAP ----------------
__global__ void bucket_init_kernel(int* __restrict__ bfill, int nbk) {
    int b = blockIdx.x * blockDim.x + threadIdx.x;
    if (b < nbk) bfill[b] = b * BCAP;
}

extern "C" void kernel_launch(void* const* d_in, const int* in_sizes, int n_in,
                              void* d_out, int out_size, void* d_ws, size_t ws_size,
                              hipStream_t stream) {
    const float* x  = (const float*)d_in[0];
    const int*   ei = (const int*)d_in[1];
    const float* W  = (const float*)d_in[2];
    const float* b  = (const float*)d_in[3];

    const int N = in_sizes[0] / F_IN;        // 100000
    const int E = in_sizes[1] / 2;           // 1280000
    const int* src = ei;
    const int* dst = ei + E;
    const int nbk = (N + (1 << BSHIFT) - 1) >> BSHIFT;   // 391

    // ---- workspace layout ----
    char* base = (char*)d_ws;
    size_t off = 0;
    auto alloc = [&](size_t bytes) {
        char* p = base + off;
        off = (off + bytes + 255) & ~(size_t)255;
        return p;
    };
    int*      deg_i   = (int*)     alloc((size_t)N * 4);
    float*    dinv    = (float*)   alloc((size_t)N * 4);
    float*    dinv2   = (float*)   alloc((size_t)N * 4);
    int*      rowptr  = (int*)     alloc((size_t)(N + 1) * 4);
    int*      bsum    = (int*)     alloc(256 * 4);
    int*      bfill   = (int*)     alloc((size_t)MAXB * 4);
    unsigned* staging = (unsigned*)alloc((size_t)nbk * BCAP * 4);    // 6.4 MB
    int*      srcs_s  = (int*)     alloc((size_t)E * 4);
    unsigned* uA      = (unsigned*)alloc((size_t)N * USTRIDE * 4);   // 8 MB
    unsigned* uB      = (unsigned*)alloc((size_t)N * USTRIDE * 4);   // 8 MB
    float*    outp    = (float*)d_out;

    const int nb = (N + SCAN_TILE - 1) / SCAN_TILE;   // 98

    // 1) partition edges into dst-buckets (fixed staging slots)
    bucket_init_kernel<<<(nbk + 255) / 256, 256, 0, stream>>>(bfill, nbk);
    partition_kernel<<<(E + PART_TILE - 1) / PART_TILE, PART_BLK, 0, stream>>>(
        src, dst, bfill, staging, E, nbk);

    // 2) degrees from staging (no global atomics), dinv
    bucket_deg_kernel<<<nbk, 256, 0, stream>>>(staging, bfill, deg_i, N);
    dinv_kernel<<<(N + 255) / 256, 256, 0, stream>>>(deg_i, dinv, dinv2, N);

    // 3) rowptr scan
    scan_a_kernel<<<nb, SCAN_BLK, 0, stream>>>(deg_i, bsum, N);
    scan_b_kernel<<<1, 256, 0, stream>>>(bsum, rowptr + N, nb);
    scan_c_kernel<<<nb, SCAN_BLK, 0, stream>>>(deg_i, bsum, rowptr, N);

    // 4) per-bucket fine scatter into CSR (LDS cursors)
    bucket_scatter_kernel<<<nbk, 256, 0, stream>>>(staging, bfill, rowptr, srcs_s, N);

    // 5) projection u0 = dinv * (x @ W^T) -> bf16 uA
    proj_kernel<<<(N + 255) / 256, 256, 0, stream>>>(x, W, dinv, uA, N);

    // 6) three pull hops in bf16 u-space: uA -> uB -> uA -> uB
    const int pt = N * F4;
    const int pg = (pt + 255) / 256;
    propagate_kernel<<<pg, 256, 0, stream>>>(rowptr, srcs_s, dinv2, uA, uB, N);
    propagate_kernel<<<pg, 256, 0, stream>>>(rowptr, srcs_s, dinv2, uB, uA, N);
    propagate_kernel<<<pg, 256, 0, stream>>>(rowptr, srcs_s, dinv2, uA, uB, N);

    // 7) y3 = D^{1/2} u3 + bias, log_softmax -> d_out (fp32)
    logsoftmax_kernel<<<(N + 255) / 256, 256, 0, stream>>>(uB, outp, b, deg_i, N);
}

// Round 8
// 237.710 us; speedup vs baseline: 4.3909x; 1.0406x over previous
//
#include <hip/hip_runtime.h>

#define F_IN 64
#define F_OUT 40
#define USTRIDE 20       // uint32 per bf16 row (40 bf16 = 80 B)
#define QPN 5            // uint4 (8 bf16) chunks per row; 5 lanes per node

#define PART_BLK 256
#define PART_EPB 16
#define PART_TILE (PART_BLK * PART_EPB)     // 4096 edges per partition block
#define BSHIFT 8                            // 256 nodes per bucket
#define BCAP 4096                           // staging slots per bucket (mean 3277, +14 sigma)
#define MAXB 512                            // >= nbk=391 (and scan width)

// ---- bf16 helpers (round-to-nearest-even, pack 2 per uint) ----
__device__ inline unsigned pk2(float x, float y) {
    unsigned a = __float_as_uint(x); a = (a + 0x7FFFu + ((a >> 16) & 1u)) >> 16;
    unsigned b = __float_as_uint(y); b = (b + 0x7FFFu + ((b >> 16) & 1u)) >> 16;
    return a | (b << 16);
}
__device__ inline void up2(unsigned u, float& a, float& b) {
    a = __uint_as_float(u << 16); b = __uint_as_float(u & 0xFFFF0000u);
}

// ---------------- bucket fill cursors start at fixed slots b*BCAP ----------------
__global__ void bucket_init_kernel(int* __restrict__ bfill, int nbk) {
    int b = blockIdx.x * blockDim.x + threadIdx.x;
    if (b < nbk) bfill[b] = b * BCAP;
}

// ---------------- phase A: multisplit partition into dst-buckets ----------------
// bucket b staging region: [b*BCAP, (b+1)*BCAP). record: src(17b) | dstLow(8b)<<17.
// Per-edge atomics are LDS-only; one global atomic per (block,bucket).
__global__ __launch_bounds__(PART_BLK) void partition_kernel(const int* __restrict__ src,
                                                             const int* __restrict__ dst,
                                                             int* __restrict__ bfill,
                                                             unsigned* __restrict__ staging,
                                                             int E, int nbk) {
    __shared__ int hist[MAXB];
    __shared__ int base[MAXB];
    int tid = threadIdx.x;
    for (int b = tid; b < nbk; b += PART_BLK) hist[b] = 0;
    __syncthreads();

    int rank[PART_EPB];
    int bk[PART_EPB];
    unsigned rec[PART_EPB];
    int eb = blockIdx.x * PART_TILE + tid;
#pragma unroll
    for (int k = 0; k < PART_EPB; ++k) {
        int e = eb + k * PART_BLK;
        if (e < E) {
            int r = src[e];
            int c = dst[e];
            int b = c >> BSHIFT;
            bk[k] = b;
            rec[k] = (unsigned)r | ((unsigned)(c & 255) << 17);
            rank[k] = atomicAdd(&hist[b], 1);
        } else {
            bk[k] = -1;
        }
    }
    __syncthreads();
    for (int b = tid; b < nbk; b += PART_BLK) {
        int h = hist[b];
        base[b] = h ? atomicAdd(&bfill[b], h) : 0;
    }
    __syncthreads();
#pragma unroll
    for (int k = 0; k < PART_EPB; ++k) {
        if (bk[k] >= 0) staging[base[bk[k]] + rank[k]] = rec[k];
    }
}

// ---------------- bucket-total scan (one block): ebase = exclusive prefix ----------------
__global__ __launch_bounds__(512) void btotal_scan_kernel(const int* __restrict__ bfill,
                                                          int* __restrict__ ebase,
                                                          int* __restrict__ rowptr_end,
                                                          int nbk, int E) {
    __shared__ int s[512];
    int tid = threadIdx.x;
    int v = (tid < nbk) ? (bfill[tid] - tid * BCAP) : 0;
    s[tid] = v;
    __syncthreads();
    for (int off = 1; off < 512; off <<= 1) {
        int t = (tid >= off) ? s[tid - off] : 0;
        __syncthreads();
        s[tid] += t;
        __syncthreads();
    }
    if (tid < nbk) ebase[tid] = s[tid] - v;
    if (tid == 0) *rowptr_end = E;
}

// ---------------- per-bucket finalize: hist -> scan -> rowptr/deg/dinv + scatter -------
__global__ __launch_bounds__(256) void bucket_finalize_kernel(const unsigned* __restrict__ staging,
                                                              const int* __restrict__ bfill,
                                                              const int* __restrict__ ebase,
                                                              int* __restrict__ rowptr,
                                                              int* __restrict__ deg,
                                                              float* __restrict__ dinv,
                                                              float* __restrict__ dinv2,
                                                              int* __restrict__ srcs, int n) {
    int b = blockIdx.x;
    __shared__ int h[256];
    __shared__ int cur[256];
    int tid = threadIdx.x;
    h[tid] = 0;
    __syncthreads();

    int cnt = bfill[b] - b * BCAP;
    const unsigned* rec = staging + (size_t)b * BCAP;
    for (int i = tid; i < cnt; i += 256) {
        atomicAdd(&h[rec[i] >> 17], 1);
    }
    __syncthreads();

    int v = h[tid];
    // inclusive Hillis-Steele scan of h
    for (int off = 1; off < 256; off <<= 1) {
        int t = (tid >= off) ? h[tid - off] : 0;
        __syncthreads();
        h[tid] += t;
        __syncthreads();
    }
    int excl = h[tid] - v;
    int base = ebase[b];
    int node = (b << BSHIFT) | tid;
    if (node < n) {
        rowptr[node] = base + excl;
        deg[node] = v;
        float r = rsqrtf((float)v + 1.0f);
        dinv[node] = r;
        dinv2[node] = r * r;
    }
    cur[tid] = base + excl;
    __syncthreads();

    for (int i = tid; i < cnt; i += 256) {
        unsigned rv = rec[i];
        int pos = atomicAdd(&cur[rv >> 17], 1);
        srcs[pos] = (int)(rv & 0x1FFFFu);
    }
}

// ---------------- projection u0 = dinv * (x @ W^T), bf16 out ----------------
__global__ __launch_bounds__(256) void proj_kernel(const float* __restrict__ x,
                                                   const float* __restrict__ W,
                                                   const float* __restrict__ dinv,
                                                   unsigned* __restrict__ u, int n) {
    __shared__ float Ws[F_OUT * F_IN];
    for (int i = threadIdx.x; i < F_OUT * F_IN; i += blockDim.x) Ws[i] = W[i];
    __syncthreads();

    int node = blockIdx.x * blockDim.x + threadIdx.x;
    if (node >= n) return;

    const float4* xp  = (const float4*)(x + (size_t)node * F_IN);
    const float4* Ws4 = (const float4*)Ws;

    float acc[F_OUT];
#pragma unroll
    for (int c = 0; c < F_OUT; ++c) acc[c] = 0.0f;
#pragma unroll
    for (int f4 = 0; f4 < F_IN / 4; ++f4) {
        float4 xv = xp[f4];
#pragma unroll
        for (int c = 0; c < F_OUT; ++c) {
            float4 w = Ws4[c * (F_IN / 4) + f4];
            acc[c] += xv.x * w.x + xv.y * w.y + xv.z * w.z + xv.w * w.w;
        }
    }
    float dv = dinv[node];
    uint4* up = (uint4*)(u + (size_t)node * USTRIDE);
#pragma unroll
    for (int g = 0; g < 5; ++g) {
        uint4 o;
        o.x = pk2(dv * acc[8 * g + 0], dv * acc[8 * g + 1]);
        o.y = pk2(dv * acc[8 * g + 2], dv * acc[8 * g + 3]);
        o.z = pk2(dv * acc[8 * g + 4], dv * acc[8 * g + 5]);
        o.w = pk2(dv * acc[8 * g + 6], dv * acc[8 * g + 7]);
        up[g] = o;
    }
}

// ---------------- pull propagation (bf16 rows, fp32 accum) ----------------
// thread t: node = t/5, q = t%5 handles one uint4 (8 bf16, 16 B) of the 80 B row.
// 500k threads = ~30 waves/CU: whole kernel co-resident in one batch.
__global__ __launch_bounds__(256) void propagate_kernel(const int* __restrict__ rowptr,
                                                        const int* __restrict__ srcs,
                                                        const float* __restrict__ dinv2,
                                                        const unsigned* __restrict__ ucur,
                                                        unsigned* __restrict__ unew, int n) {
    int t = blockIdx.x * blockDim.x + threadIdx.x;
    int node = t / QPN;
    int q = t - node * QPN;
    if (node >= n) return;

    int beg = rowptr[node];
    int end = rowptr[node + 1];

    const uint4* U = (const uint4*)ucur;    // row = 5 uint4
    uint4 sv = U[(size_t)node * QPN + q];   // self loop
    float a0, a1, a2, a3, a4, a5, a6, a7;
    up2(sv.x, a0, a1); up2(sv.y, a2, a3); up2(sv.z, a4, a5); up2(sv.w, a6, a7);

    int i = beg;
    for (; i + 3 < end; i += 4) {
        int s0 = srcs[i], s1 = srcs[i + 1], s2 = srcs[i + 2], s3 = srcs[i + 3];
        uint4 v0 = U[(size_t)s0 * QPN + q];
        uint4 v1 = U[(size_t)s1 * QPN + q];
        uint4 v2 = U[(size_t)s2 * QPN + q];
        uint4 v3 = U[(size_t)s3 * QPN + q];
        float b0, b1;
        up2(v0.x, b0, b1); a0 += b0; a1 += b1;
        up2(v0.y, b0, b1); a2 += b0; a3 += b1;
        up2(v0.z, b0, b1); a4 += b0; a5 += b1;
        up2(v0.w, b0, b1); a6 += b0; a7 += b1;
        up2(v1.x, b0, b1); a0 += b0; a1 += b1;
        up2(v1.y, b0, b1); a2 += b0; a3 += b1;
        up2(v1.z, b0, b1); a4 += b0; a5 += b1;
        up2(v1.w, b0, b1); a6 += b0; a7 += b1;
        up2(v2.x, b0, b1); a0 += b0; a1 += b1;
        up2(v2.y, b0, b1); a2 += b0; a3 += b1;
        up2(v2.z, b0, b1); a4 += b0; a5 += b1;
        up2(v2.w, b0, b1); a6 += b0; a7 += b1;
        up2(v3.x, b0, b1); a0 += b0; a1 += b1;
        up2(v3.y, b0, b1); a2 += b0; a3 += b1;
        up2(v3.z, b0, b1); a4 += b0; a5 += b1;
        up2(v3.w, b0, b1); a6 += b0; a7 += b1;
    }
    for (; i < end; ++i) {
        uint4 v = U[(size_t)srcs[i] * QPN + q];
        float b0, b1;
        up2(v.x, b0, b1); a0 += b0; a1 += b1;
        up2(v.y, b0, b1); a2 += b0; a3 += b1;
        up2(v.z, b0, b1); a4 += b0; a5 += b1;
        up2(v.w, b0, b1); a6 += b0; a7 += b1;
    }

    float ds = dinv2[node];
    uint4 o;
    o.x = pk2(ds * a0, ds * a1);
    o.y = pk2(ds * a2, ds * a3);
    o.z = pk2(ds * a4, ds * a5);
    o.w = pk2(ds * a6, ds * a7);
    ((uint4*)unew)[(size_t)node * QPN + q] = o;
}

// ---------------- y = D^{1/2} u3 + bias, log_softmax -> fp32 d_out ----------------
__global__ void logsoftmax_kernel(const unsigned* __restrict__ u, float* __restrict__ out,
                                  const float* __restrict__ bias,
                                  const int* __restrict__ deg, int n) {
    int node = blockIdx.x * blockDim.x + threadIdx.x;
    if (node >= n) return;
    float sq = sqrtf((float)deg[node] + 1.0f);
    const uint4* up = (const uint4*)(u + (size_t)node * USTRIDE);
    float v[F_OUT];
#pragma unroll
    for (int g = 0; g < 5; ++g) {
        uint4 t = up[g];
        float a, b2;
        up2(t.x, a, b2); v[8 * g + 0] = sq * a + bias[8 * g + 0];
                         v[8 * g + 1] = sq * b2 + bias[8 * g + 1];
        up2(t.y, a, b2); v[8 * g + 2] = sq * a + bias[8 * g + 2];
                         v[8 * g + 3] = sq * b2 + bias[8 * g + 3];
        up2(t.z, a, b2); v[8 * g + 4] = sq * a + bias[8 * g + 4];
                         v[8 * g + 5] = sq * b2 + bias[8 * g + 5];
        up2(t.w, a, b2); v[8 * g + 6] = sq * a + bias[8 * g + 6];
                         v[8 * g + 7] = sq * b2 + bias[8 * g + 7];
    }
    float mx = -1e30f;
#pragma unroll
    for (int c = 0; c < F_OUT; ++c) mx = fmaxf(mx, v[c]);
    float se = 0.0f;
#pragma unroll
    for (int c = 0; c < F_OUT; ++c) se += __expf(v[c] - mx);
    float lse = mx + __logf(se);
    float4* p = (float4*)(out + (size_t)node * F_OUT);
#pragma unroll
    for (int c4 = 0; c4 < F_OUT / 4; ++c4) {
        float4 t;
        t.x = v[4 * c4 + 0] - lse; t.y = v[4 * c4 + 1] - lse;
        t.z = v[4 * c4 + 2] - lse; t.w = v[4 * c4 + 3] - lse;
        p[c4] = t;
    }
}

extern "C" void kernel_launch(void* const* d_in, const int* in_sizes, int n_in,
                              void* d_out, int out_size, void* d_ws, size_t ws_size,
                              hipStream_t stream) {
    const float* x  = (const float*)d_in[0];
    const int*   ei = (const int*)d_in[1];
    const float* W  = (const float*)d_in[2];
    const float* b  = (const float*)d_in[3];

    const int N = in_sizes[0] / F_IN;        // 100000
    const int E = in_sizes[1] / 2;           // 1280000
    const int* src = ei;
    const int* dst = ei + E;
    const int nbk = (N + (1 << BSHIFT) - 1) >> BSHIFT;   // 391

    // ---- workspace layout ----
    char* base = (char*)d_ws;
    size_t off = 0;
    auto alloc = [&](size_t bytes) {
        char* p = base + off;
        off = (off + bytes + 255) & ~(size_t)255;
        return p;
    };
    int*      deg_i   = (int*)     alloc((size_t)N * 4);
    float*    dinv    = (float*)   alloc((size_t)N * 4);
    float*    dinv2   = (float*)   alloc((size_t)N * 4);
    int*      rowptr  = (int*)     alloc((size_t)(N + 1) * 4);
    int*      bfill   = (int*)     alloc((size_t)MAXB * 4);
    int*      ebase   = (int*)     alloc((size_t)MAXB * 4);
    unsigned* staging = (unsigned*)alloc((size_t)nbk * BCAP * 4);    // 6.4 MB
    int*      srcs_s  = (int*)     alloc((size_t)E * 4);
    unsigned* uA      = (unsigned*)alloc((size_t)N * USTRIDE * 4);   // 8 MB
    unsigned* uB      = (unsigned*)alloc((size_t)N * USTRIDE * 4);   // 8 MB
    float*    outp    = (float*)d_out;

    // 1) partition edges into dst-buckets (fixed staging slots)
    bucket_init_kernel<<<(nbk + 255) / 256, 256, 0, stream>>>(bfill, nbk);
    partition_kernel<<<(E + PART_TILE - 1) / PART_TILE, PART_BLK, 0, stream>>>(
        src, dst, bfill, staging, E, nbk);

    // 2) bucket-total scan + per-bucket finalize (rowptr/deg/dinv + CSR scatter)
    btotal_scan_kernel<<<1, 512, 0, stream>>>(bfill, ebase, rowptr + N, nbk, E);
    bucket_finalize_kernel<<<nbk, 256, 0, stream>>>(staging, bfill, ebase, rowptr,
                                                    deg_i, dinv, dinv2, srcs_s, N);

    // 3) projection u0 = dinv * (x @ W^T) -> bf16 uA
    proj_kernel<<<(N + 255) / 256, 256, 0, stream>>>(x, W, dinv, uA, N);

    // 4) three pull hops in bf16 u-space: uA -> uB -> uA -> uB
    const int pt = N * QPN;                  // 500k threads
    const int pg = (pt + 255) / 256;
    propagate_kernel<<<pg, 256, 0, stream>>>(rowptr, srcs_s, dinv2, uA, uB, N);
    propagate_kernel<<<pg, 256, 0, stream>>>(rowptr, srcs_s, dinv2, uB, uA, N);
    propagate_kernel<<<pg, 256, 0, stream>>>(rowptr, srcs_s, dinv2, uA, uB, N);

    // 5) y3 = D^{1/2} u3 + bias, log_softmax -> d_out (fp32)
    logsoftmax_kernel<<<(N + 255) / 256, 256, 0, stream>>>(uB, outp, b, deg_i, N);
}

// Round 9
// 218.094 us; speedup vs baseline: 4.7858x; 1.0899x over previous
//
#include <hip/hip_runtime.h>

#define F_IN 64
#define F_OUT 40
#define USTRIDE 20       // uint32 per bf16 row (40 bf16 = 80 B)
#define QPN 5            // uint4 (8 bf16) chunks per row; 5 lanes per node

#define PART_BLK 256
#define PART_EPB 16
#define PART_TILE (PART_BLK * PART_EPB)     // 4096 edges per partition block
#define BSHIFT 8                            // 256 nodes per bucket
#define BCAP 4096                           // staging slots per bucket (mean 3277, +14 sigma)
#define MAXB 512                            // >= nbk=391 (and scan width)

#define WSTRIDE 17                          // W LDS row stride in float4 (bank-conflict-free)

// ---- bf16 helpers (round-to-nearest-even, pack 2 per uint) ----
__device__ inline unsigned pk2(float x, float y) {
    unsigned a = __float_as_uint(x); a = (a + 0x7FFFu + ((a >> 16) & 1u)) >> 16;
    unsigned b = __float_as_uint(y); b = (b + 0x7FFFu + ((b >> 16) & 1u)) >> 16;
    return a | (b << 16);
}
__device__ inline void up2(unsigned u, float& a, float& b) {
    a = __uint_as_float(u << 16); b = __uint_as_float(u & 0xFFFF0000u);
}

// ---------------- bucket fill cursors start at fixed slots b*BCAP ----------------
__global__ void bucket_init_kernel(int* __restrict__ bfill, int nbk) {
    int b = blockIdx.x * blockDim.x + threadIdx.x;
    if (b < nbk) bfill[b] = b * BCAP;
}

// ---------------- phase A: multisplit partition into dst-buckets ----------------
// bucket b staging region: [b*BCAP, (b+1)*BCAP). record: src(17b) | dstLow(8b)<<17.
// Per-edge atomics are LDS-only; one global atomic per (block,bucket).
__global__ __launch_bounds__(PART_BLK) void partition_kernel(const int* __restrict__ src,
                                                             const int* __restrict__ dst,
                                                             int* __restrict__ bfill,
                                                             unsigned* __restrict__ staging,
                                                             int E, int nbk) {
    __shared__ int hist[MAXB];
    __shared__ int base[MAXB];
    int tid = threadIdx.x;
    for (int b = tid; b < nbk; b += PART_BLK) hist[b] = 0;
    __syncthreads();

    int rank[PART_EPB];
    int bk[PART_EPB];
    unsigned rec[PART_EPB];
    int eb = blockIdx.x * PART_TILE + tid;
#pragma unroll
    for (int k = 0; k < PART_EPB; ++k) {
        int e = eb + k * PART_BLK;
        if (e < E) {
            int r = src[e];
            int c = dst[e];
            int b = c >> BSHIFT;
            bk[k] = b;
            rec[k] = (unsigned)r | ((unsigned)(c & 255) << 17);
            rank[k] = atomicAdd(&hist[b], 1);
        } else {
            bk[k] = -1;
        }
    }
    __syncthreads();
    for (int b = tid; b < nbk; b += PART_BLK) {
        int h = hist[b];
        base[b] = h ? atomicAdd(&bfill[b], h) : 0;
    }
    __syncthreads();
#pragma unroll
    for (int k = 0; k < PART_EPB; ++k) {
        if (bk[k] >= 0) staging[base[bk[k]] + rank[k]] = rec[k];
    }
}

// ---------------- bucket-total scan (one block): ebase = exclusive prefix ----------------
__global__ __launch_bounds__(512) void btotal_scan_kernel(const int* __restrict__ bfill,
                                                          int* __restrict__ ebase,
                                                          int* __restrict__ rowptr_end,
                                                          int nbk, int E) {
    __shared__ int s[512];
    int tid = threadIdx.x;
    int v = (tid < nbk) ? (bfill[tid] - tid * BCAP) : 0;
    s[tid] = v;
    __syncthreads();
    for (int off = 1; off < 512; off <<= 1) {
        int t = (tid >= off) ? s[tid - off] : 0;
        __syncthreads();
        s[tid] += t;
        __syncthreads();
    }
    if (tid < nbk) ebase[tid] = s[tid] - v;
    if (tid == 0) *rowptr_end = E;
}

// ---------------- per-bucket finalize: hist -> scan -> rowptr/deg/dinv + scatter -------
__global__ __launch_bounds__(256) void bucket_finalize_kernel(const unsigned* __restrict__ staging,
                                                              const int* __restrict__ bfill,
                                                              const int* __restrict__ ebase,
                                                              int* __restrict__ rowptr,
                                                              int* __restrict__ deg,
                                                              float* __restrict__ dinv,
                                                              float* __restrict__ dinv2,
                                                              int* __restrict__ srcs, int n) {
    int b = blockIdx.x;
    __shared__ int h[256];
    __shared__ int cur[256];
    int tid = threadIdx.x;
    h[tid] = 0;
    __syncthreads();

    int cnt = bfill[b] - b * BCAP;
    const unsigned* rec = staging + (size_t)b * BCAP;
    for (int i = tid; i < cnt; i += 256) {
        atomicAdd(&h[rec[i] >> 17], 1);
    }
    __syncthreads();

    int v = h[tid];
    // inclusive Hillis-Steele scan of h
    for (int off = 1; off < 256; off <<= 1) {
        int t = (tid >= off) ? h[tid - off] : 0;
        __syncthreads();
        h[tid] += t;
        __syncthreads();
    }
    int excl = h[tid] - v;
    int base = ebase[b];
    int node = (b << BSHIFT) | tid;
    if (node < n) {
        rowptr[node] = base + excl;
        deg[node] = v;
        float r = rsqrtf((float)v + 1.0f);
        dinv[node] = r;
        dinv2[node] = r * r;
    }
    cur[tid] = base + excl;
    __syncthreads();

    for (int i = tid; i < cnt; i += 256) {
        unsigned rv = rec[i];
        int pos = atomicAdd(&cur[rv >> 17], 1);
        srcs[pos] = (int)(rv & 0x1FFFFu);
    }
}

// ---------------- projection u0 = dinv * (x @ W^T), bf16 out ----------------
// 4 threads per node (q = t&3), 10 channels each: 10 accumulators, ~50 VGPR,
// 1563 blocks. W in LDS with row stride 17 float4 so the 4 q-groups hit
// disjoint bank quartets (stride 680 B = +8 banks per q) -> no conflicts.
__global__ __launch_bounds__(256, 6) void proj_kernel(const float* __restrict__ x,
                                                      const float* __restrict__ W,
                                                      const float* __restrict__ dinv,
                                                      unsigned* __restrict__ u, int n) {
    __shared__ float Ws[F_OUT * WSTRIDE * 4];
    for (int i = threadIdx.x; i < F_OUT * F_IN; i += 256) {
        int c = i >> 6;
        int k = i & 63;
        Ws[c * (WSTRIDE * 4) + k] = W[i];
    }
    __syncthreads();

    int t = blockIdx.x * 256 + threadIdx.x;
    int node = t >> 2;
    int q = t & 3;
    if (node >= n) return;

    const float4* xp = (const float4*)(x + (size_t)node * F_IN);
    const float4* Wq = (const float4*)Ws + (size_t)(q * 10) * WSTRIDE;

    float acc[10];
#pragma unroll
    for (int c = 0; c < 10; ++c) acc[c] = 0.0f;

#pragma unroll 1
    for (int f4 = 0; f4 < F_IN / 4; ++f4) {
        float4 xv = xp[f4];
#pragma unroll
        for (int c = 0; c < 10; ++c) {
            float4 w = Wq[c * WSTRIDE + f4];
            acc[c] += xv.x * w.x + xv.y * w.y + xv.z * w.z + xv.w * w.w;
        }
    }

    float dv = dinv[node];
    unsigned* up = u + (size_t)node * USTRIDE + q * 5;
#pragma unroll
    for (int j = 0; j < 5; ++j) {
        up[j] = pk2(dv * acc[2 * j], dv * acc[2 * j + 1]);
    }
}

// ---------------- pull propagation (bf16 rows, fp32 accum) ----------------
// thread t: node = t/5, q = t%5 handles one uint4 (8 bf16, 16 B) of the 80 B row.
// 500k threads = ~30 waves/CU: whole kernel co-resident in one batch.
__global__ __launch_bounds__(256) void propagate_kernel(const int* __restrict__ rowptr,
                                                        const int* __restrict__ srcs,
                                                        const float* __restrict__ dinv2,
                                                        const unsigned* __restrict__ ucur,
                                                        unsigned* __restrict__ unew, int n) {
    int t = blockIdx.x * blockDim.x + threadIdx.x;
    int node = t / QPN;
    int q = t - node * QPN;
    if (node >= n) return;

    int beg = rowptr[node];
    int end = rowptr[node + 1];

    const uint4* U = (const uint4*)ucur;    // row = 5 uint4
    uint4 sv = U[(size_t)node * QPN + q];   // self loop
    float a0, a1, a2, a3, a4, a5, a6, a7;
    up2(sv.x, a0, a1); up2(sv.y, a2, a3); up2(sv.z, a4, a5); up2(sv.w, a6, a7);

    int i = beg;
    for (; i + 3 < end; i += 4) {
        int s0 = srcs[i], s1 = srcs[i + 1], s2 = srcs[i + 2], s3 = srcs[i + 3];
        uint4 v0 = U[(size_t)s0 * QPN + q];
        uint4 v1 = U[(size_t)s1 * QPN + q];
        uint4 v2 = U[(size_t)s2 * QPN + q];
        uint4 v3 = U[(size_t)s3 * QPN + q];
        float b0, b1;
        up2(v0.x, b0, b1); a0 += b0; a1 += b1;
        up2(v0.y, b0, b1); a2 += b0; a3 += b1;
        up2(v0.z, b0, b1); a4 += b0; a5 += b1;
        up2(v0.w, b0, b1); a6 += b0; a7 += b1;
        up2(v1.x, b0, b1); a0 += b0; a1 += b1;
        up2(v1.y, b0, b1); a2 += b0; a3 += b1;
        up2(v1.z, b0, b1); a4 += b0; a5 += b1;
        up2(v1.w, b0, b1); a6 += b0; a7 += b1;
        up2(v2.x, b0, b1); a0 += b0; a1 += b1;
        up2(v2.y, b0, b1); a2 += b0; a3 += b1;
        up2(v2.z, b0, b1); a4 += b0; a5 += b1;
        up2(v2.w, b0, b1); a6 += b0; a7 += b1;
        up2(v3.x, b0, b1); a0 += b0; a1 += b1;
        up2(v3.y, b0, b1); a2 += b0; a3 += b1;
        up2(v3.z, b0, b1); a4 += b0; a5 += b1;
        up2(v3.w, b0, b1); a6 += b0; a7 += b1;
    }
    for (; i < end; ++i) {
        uint4 v = U[(size_t)srcs[i] * QPN + q];
        float b0, b1;
        up2(v.x, b0, b1); a0 += b0; a1 += b1;
        up2(v.y, b0, b1); a2 += b0; a3 += b1;
        up2(v.z, b0, b1); a4 += b0; a5 += b1;
        up2(v.w, b0, b1); a6 += b0; a7 += b1;
    }

    float ds = dinv2[node];
    uint4 o;
    o.x = pk2(ds * a0, ds * a1);
    o.y = pk2(ds * a2, ds * a3);
    o.z = pk2(ds * a4, ds * a5);
    o.w = pk2(ds * a6, ds * a7);
    ((uint4*)unew)[(size_t)node * QPN + q] = o;
}

// ---------------- y = D^{1/2} u3 + bias, log_softmax -> fp32 d_out ----------------
__global__ void logsoftmax_kernel(const unsigned* __restrict__ u, float* __restrict__ out,
                                  const float* __restrict__ bias,
                                  const int* __restrict__ deg, int n) {
    int node = blockIdx.x * blockDim.x + threadIdx.x;
    if (node >= n) return;
    float sq = sqrtf((float)deg[node] + 1.0f);
    const uint4* up = (const uint4*)(u + (size_t)node * USTRIDE);
    float v[F_OUT];
#pragma unroll
    for (int g = 0; g < 5; ++g) {
        uint4 t = up[g];
        float a, b2;
        up2(t.x, a, b2); v[8 * g + 0] = sq * a + bias[8 * g + 0];
                         v[8 * g + 1] = sq * b2 + bias[8 * g + 1];
        up2(t.y, a, b2); v[8 * g + 2] = sq * a + bias[8 * g + 2];
                         v[8 * g + 3] = sq * b2 + bias[8 * g + 3];
        up2(t.z, a, b2); v[8 * g + 4] = sq * a + bias[8 * g + 4];
                         v[8 * g + 5] = sq * b2 + bias[8 * g + 5];
        up2(t.w, a, b2); v[8 * g + 6] = sq * a + bias[8 * g + 6];
                         v[8 * g + 7] = sq * b2 + bias[8 * g + 7];
    }
    float mx = -1e30f;
#pragma unroll
    for (int c = 0; c < F_OUT; ++c) mx = fmaxf(mx, v[c]);
    float se = 0.0f;
#pragma unroll
    for (int c = 0; c < F_OUT; ++c) se += __expf(v[c] - mx);
    float lse = mx + __logf(se);
    float4* p = (float4*)(out + (size_t)node * F_OUT);
#pragma unroll
    for (int c4 = 0; c4 < F_OUT / 4; ++c4) {
        float4 t;
        t.x = v[4 * c4 + 0] - lse; t.y = v[4 * c4 + 1] - lse;
        t.z = v[4 * c4 + 2] - lse; t.w = v[4 * c4 + 3] - lse;
        p[c4] = t;
    }
}

extern "C" void kernel_launch(void* const* d_in, const int* in_sizes, int n_in,
                              void* d_out, int out_size, void* d_ws, size_t ws_size,
                              hipStream_t stream) {
    const float* x  = (const float*)d_in[0];
    const int*   ei = (const int*)d_in[1];
    const float* W  = (const float*)d_in[2];
    const float* b  = (const float*)d_in[3];

    const int N = in_sizes[0] / F_IN;        // 100000
    const int E = in_sizes[1] / 2;           // 1280000
    const int* src = ei;
    const int* dst = ei + E;
    const int nbk = (N + (1 << BSHIFT) - 1) >> BSHIFT;   // 391

    // ---- workspace layout ----
    char* base = (char*)d_ws;
    size_t off = 0;
    auto alloc = [&](size_t bytes) {
        char* p = base + off;
        off = (off + bytes + 255) & ~(size_t)255;
        return p;
    };
    int*      deg_i   = (int*)     alloc((size_t)N * 4);
    float*    dinv    = (float*)   alloc((size_t)N * 4);
    float*    dinv2   = (float*)   alloc((size_t)N * 4);
    int*      rowptr  = (int*)     alloc((size_t)(N + 1) * 4);
    int*      bfill   = (int*)     alloc((size_t)MAXB * 4);
    int*      ebase   = (int*)     alloc((size_t)MAXB * 4);
    unsigned* staging = (unsigned*)alloc((size_t)nbk * BCAP * 4);    // 6.4 MB
    int*      srcs_s  = (int*)     alloc((size_t)E * 4);
    unsigned* uA      = (unsigned*)alloc((size_t)N * USTRIDE * 4);   // 8 MB
    unsigned* uB      = (unsigned*)alloc((size_t)N * USTRIDE * 4);   // 8 MB
    float*    outp    = (float*)d_out;

    // 1) partition edges into dst-buckets (fixed staging slots)
    bucket_init_kernel<<<(nbk + 255) / 256, 256, 0, stream>>>(bfill, nbk);
    partition_kernel<<<(E + PART_TILE - 1) / PART_TILE, PART_BLK, 0, stream>>>(
        src, dst, bfill, staging, E, nbk);

    // 2) bucket-total scan + per-bucket finalize (rowptr/deg/dinv + CSR scatter)
    btotal_scan_kernel<<<1, 512, 0, stream>>>(bfill, ebase, rowptr + N, nbk, E);
    bucket_finalize_kernel<<<nbk, 256, 0, stream>>>(staging, bfill, ebase, rowptr,
                                                    deg_i, dinv, dinv2, srcs_s, N);

    // 3) projection u0 = dinv * (x @ W^T) -> bf16 uA  (4 threads/node)
    proj_kernel<<<((size_t)N * 4 + 255) / 256, 256, 0, stream>>>(x, W, dinv, uA, N);

    // 4) three pull hops in bf16 u-space: uA -> uB -> uA -> uB
    const int pt = N * QPN;                  // 500k threads
    const int pg = (pt + 255) / 256;
    propagate_kernel<<<pg, 256, 0, stream>>>(rowptr, srcs_s, dinv2, uA, uB, N);
    propagate_kernel<<<pg, 256, 0, stream>>>(rowptr, srcs_s, dinv2, uB, uA, N);
    propagate_kernel<<<pg, 256, 0, stream>>>(rowptr, srcs_s, dinv2, uA, uB, N);

    // 5) y3 = D^{1/2} u3 + bias, log_softmax -> d_out (fp32)
    logsoftmax_kernel<<<(N + 255) / 256, 256, 0, stream>>>(uB, outp, b, deg_i, N);
}